// Round 11
// baseline (145.630 us; speedup 1.0000x reference)
//
#include <hip/hip_runtime.h>
#include <math.h>

#define DIM 256
#define BATCH 16
#define NO 64
#define NI 512
#define NEG_SLOPE 0.01f
#define CSCALE 2.885390081777927f   // 2*log2(e): tanh(x) = 1 - 2/(exp2(CSCALE*x)+1)
#define OT 4                        // o's per attn THREAD (one Ek load serves 4 o)

// ---------------------------------------------------------------------------
// Kernel 1 (blocks 0..575): GEMM  out[r,h] = sum_d A[r,d] * W1[h, coff+d]
//   rows 0..1023    -> Eq[bo][h]        = exp2(CSCALE*(acc + b1[h]))  (A = q)
//   rows 1024..9215 -> Ek4[b][h/4][i][4]= exp2(CSCALE*acc)            (A = k)
// exp factorization: e^{2(qp+kp+b1)} = Eq * Ek -> attn sigmoid = fma+rcp.
// 64x64 tile, K-chunk 64, 4x4 microtile. Blocks 576..591: Wf -> WfT.
// ---------------------------------------------------------------------------
__global__ __launch_bounds__(256, 4) void proj_kernel(
    const float* __restrict__ q, const float* __restrict__ k,
    const float* __restrict__ W1, const float* __restrict__ b1,
    const float* __restrict__ Wf,
    float* __restrict__ Eq, float* __restrict__ Ek4, float* __restrict__ WfT)
{
  __shared__ float smem[8704];   // 34 KB: At[64][68] + Wt[64][68]

  const int t  = threadIdx.x;
  const int bx = blockIdx.x;

  if (bx >= 576) {
    const int tt = bx - 576;
    const int tr = tt >> 2, tc = tt & 3;
#pragma unroll
    for (int p = 0; p < 4; ++p) {
      int idx = p * 256 + t;
      int row = idx >> 4, j = idx & 15;
      float4 vv = *(const float4*)(Wf + (size_t)(tr * 64 + row) * 256 + tc * 64 + j * 4);
      *(float4*)&smem[row * 68 + j * 4] = vv;
    }
    __syncthreads();
#pragma unroll
    for (int p = 0; p < 4; ++p) {
      int idx = p * 256 + t;
      int row = idx >> 4, j = idx & 15;
      float4 ov;
      ov.x = smem[(j * 4 + 0) * 68 + row];
      ov.y = smem[(j * 4 + 1) * 68 + row];
      ov.z = smem[(j * 4 + 2) * 68 + row];
      ov.w = smem[(j * 4 + 3) * 68 + row];
      *(float4*)(WfT + (size_t)(tc * 64 + row) * 256 + tr * 64 + j * 4) = ov;
    }
    return;
  }

  float* At = smem;            // At[dk][row], stride 68
  float* Wt = smem + 4352;     // Wt[dk][h],   stride 68

  const int tx = t & 15;
  const int ty = t >> 4;
  const int mt = bx >> 2;
  const int nt = bx & 3;
  const int r0 = mt * 64;
  const int h0 = nt * 64;
  const bool isq = (r0 < BATCH * NO);
  const float* src = isq ? (q + (size_t)r0 * DIM)
                         : (k + (size_t)(r0 - BATCH * NO) * DIM);
  const int coff = isq ? 0 : DIM;

  float acc[4][4] = {};

  for (int c0 = 0; c0 < DIM; c0 += 64) {
    __syncthreads();
#pragma unroll
    for (int p = 0; p < 4; ++p) {
      int idx = p * 256 + t;
      int row = idx >> 4, j = idx & 15;
      float4 av = *(const float4*)(src + (size_t)row * DIM + c0 + j * 4);
      At[(4 * j + 0) * 68 + row] = av.x;
      At[(4 * j + 1) * 68 + row] = av.y;
      At[(4 * j + 2) * 68 + row] = av.z;
      At[(4 * j + 3) * 68 + row] = av.w;
      float4 wv = *(const float4*)(W1 + (size_t)(h0 + row) * (2 * DIM) + coff + c0 + j * 4);
      Wt[(4 * j + 0) * 68 + row] = wv.x;
      Wt[(4 * j + 1) * 68 + row] = wv.y;
      Wt[(4 * j + 2) * 68 + row] = wv.z;
      Wt[(4 * j + 3) * 68 + row] = wv.w;
    }
    __syncthreads();
#pragma unroll
    for (int dk = 0; dk < 64; ++dk) {
      float4 a4 = *(const float4*)&At[dk * 68 + ty * 4];
      float4 w4 = *(const float4*)&Wt[dk * 68 + tx * 4];
      const float ar[4] = {a4.x, a4.y, a4.z, a4.w};
      const float wr[4] = {w4.x, w4.y, w4.z, w4.w};
#pragma unroll
      for (int rr = 0; rr < 4; ++rr)
#pragma unroll
        for (int cc = 0; cc < 4; ++cc)
          acc[rr][cc] = fmaf(ar[rr], wr[cc], acc[rr][cc]);
    }
  }

  if (isq) {
    float4 bv = *(const float4*)(b1 + h0 + tx * 4);
    const float br[4] = {bv.x, bv.y, bv.z, bv.w};
#pragma unroll
    for (int rr = 0; rr < 4; ++rr) {
      int r = r0 + ty * 4 + rr;
      float4 ov;
      ov.x = __builtin_amdgcn_exp2f((acc[rr][0] + br[0]) * CSCALE);
      ov.y = __builtin_amdgcn_exp2f((acc[rr][1] + br[1]) * CSCALE);
      ov.z = __builtin_amdgcn_exp2f((acc[rr][2] + br[2]) * CSCALE);
      ov.w = __builtin_amdgcn_exp2f((acc[rr][3] + br[3]) * CSCALE);
      *(float4*)(Eq + (size_t)r * DIM + h0 + tx * 4) = ov;
    }
  } else {
    // Ek4 layout: Ek4[((b*64 + h/4)*NI + i)*4 + (h&3)]
    int ig0 = r0 - BATCH * NO;
    int b   = ig0 >> 9;
    int i0  = (ig0 & 511) + ty * 4;
    int hq0 = (h0 >> 2) + tx;          // this thread's h-quad
#pragma unroll
    for (int rr = 0; rr < 4; ++rr) {
      float4 ov;
      ov.x = __builtin_amdgcn_exp2f(acc[rr][0] * CSCALE);
      ov.y = __builtin_amdgcn_exp2f(acc[rr][1] * CSCALE);
      ov.z = __builtin_amdgcn_exp2f(acc[rr][2] * CSCALE);
      ov.w = __builtin_amdgcn_exp2f(acc[rr][3] * CSCALE);
      *(float4*)(Ek4 + ((size_t)(b * 64 + hq0) * NI + i0 + rr) * 4) = ov;
    }
  }
}

__device__ __forceinline__ void f4arr(float4 v, float* a) {
  a[0] = v.x; a[1] = v.y; a[2] = v.z; a[3] = v.w;
}

// ---------------------------------------------------------------------------
// Kernel 2: one block (512 threads) per (b, o-quad). Grid 256, XCD-swizzled
// (2 b's per XCD -> Ek+v slice ~2.3 MB < 4 MB L2).
// phase 1: thread = one i, FOUR o's: one Ek4 float4 load serves 4 h x 4 o
//          (16 sigmoids) -> Ek L2 traffic halves vs OT=2.
// phase 2: 4 softmaxes, NO max-subtraction (|s| <= sum|W2|+|b2| ~ 13, safe).
// phase 3: PV once per block for 4 o. phase 4: WfT column shared by 2 o.
// ---------------------------------------------------------------------------
__global__ __launch_bounds__(512, 2) void attn_kernel(
    const float* __restrict__ Eq, const float* __restrict__ Ek4,
    const float* __restrict__ v, const int* __restrict__ mask,
    const float* __restrict__ W2, const float* __restrict__ b2,
    const float* __restrict__ WfT, const float* __restrict__ bf,
    float* __restrict__ out, float* __restrict__ attn_out)
{
  __shared__ float sc[OT][NI];        // 8 KB
  __shared__ float pvp[8][OT][DIM];   // 32 KB
  __shared__ float o0[OT][DIM];       // 4 KB
  __shared__ float red4[8][OT];
  __shared__ float redw[8];

  const int t    = threadIdx.x;
  const int lane = t & 63;
  const int wid  = t >> 6;

  const int blk  = blockIdx.x;
  const int tile = (blk & 7) * 32 + (blk >> 3);   // XCD swizzle
  const int b    = tile >> 4;
  const int bo0  = b * 64 + (tile & 15) * OT;

  // ---- sumW2 ----
  float partial = (t < DIM) ? W2[t] : 0.f;
#pragma unroll
  for (int off = 32; off >= 1; off >>= 1) partial += __shfl_xor(partial, off, 64);
  if (lane == 0) redw[wid] = partial;
  __syncthreads();
  float sumw2 = 0.f;
#pragma unroll
  for (int w = 0; w < 8; ++w) sumw2 += redw[w];
  const float base = sumw2 + b2[0];

  // ---- phase 1: scores s[0..3] for i = t ----
  const int i = t;
  const float4* kb4 = (const float4*)Ek4 + (size_t)b * 64 * NI;  // [hq*NI + i]
  const float* qrow0 = Eq + (size_t)(bo0 + 0) * DIM;
  const float* qrow1 = Eq + (size_t)(bo0 + 1) * DIM;
  const float* qrow2 = Eq + (size_t)(bo0 + 2) * DIM;
  const float* qrow3 = Eq + (size_t)(bo0 + 3) * DIM;

  float acc0 = 0.f, acc1 = 0.f, acc2 = 0.f, acc3 = 0.f;
#pragma unroll 4
  for (int hq = 0; hq < 64; ++hq) {
    float4 kq = kb4[(size_t)hq * NI + i];
    float wr[4], q0r[4], q1r[4], q2r[4], q3r[4], kv[4];
    f4arr(*(const float4*)(W2 + hq * 4), wr);        // wave-uniform -> s_load
    f4arr(*(const float4*)(qrow0 + hq * 4), q0r);
    f4arr(*(const float4*)(qrow1 + hq * 4), q1r);
    f4arr(*(const float4*)(qrow2 + hq * 4), q2r);
    f4arr(*(const float4*)(qrow3 + hq * 4), q3r);
    f4arr(kq, kv);
#pragma unroll
    for (int e = 0; e < 4; ++e) {
      float d0 = fmaf(q0r[e], kv[e], 1.f);
      acc0 = fmaf(wr[e], __builtin_amdgcn_rcpf(d0), acc0);
      float d1 = fmaf(q1r[e], kv[e], 1.f);
      acc1 = fmaf(wr[e], __builtin_amdgcn_rcpf(d1), acc1);
      float d2 = fmaf(q2r[e], kv[e], 1.f);
      acc2 = fmaf(wr[e], __builtin_amdgcn_rcpf(d2), acc2);
      float d3 = fmaf(q3r[e], kv[e], 1.f);
      acc3 = fmaf(wr[e], __builtin_amdgcn_rcpf(d3), acc3);
    }
  }

  const int mv = mask[(size_t)b * NI + i];
  float s[OT];
  s[0] = base - 2.f * acc0;
  s[1] = base - 2.f * acc1;
  s[2] = base - 2.f * acc2;
  s[3] = base - 2.f * acc3;
  if (mv) { s[0] = -INFINITY; s[1] = -INFINITY; s[2] = -INFINITY; s[3] = -INFINITY; }

  // ---- phase 2: 4 softmaxes over 512 lanes, no max-subtraction ----
  // |s| <= sum|W2| + |b2| ~ 13 -> exp2 is overflow/underflow-safe.
  float p[OT], ps[OT];
#pragma unroll
  for (int oo = 0; oo < OT; ++oo) {
    p[oo] = __builtin_amdgcn_exp2f(s[oo] * 1.4426950408889634f);  // exp(-inf)=0
    ps[oo] = p[oo];
#pragma unroll
    for (int off = 32; off >= 1; off >>= 1) ps[oo] += __shfl_xor(ps[oo], off, 64);
  }
  __syncthreads();               // redw reads done; red4 safe
  if (lane == 0) {
#pragma unroll
    for (int oo = 0; oo < OT; ++oo) red4[wid][oo] = ps[oo];
  }
  __syncthreads();
#pragma unroll
  for (int oo = 0; oo < OT; ++oo) {
    float ss = 0.f;
#pragma unroll
    for (int w = 0; w < 8; ++w) ss += red4[w][oo];
    float a = p[oo] * __builtin_amdgcn_rcpf(ss);
    sc[oo][i] = a;
    attn_out[(size_t)(bo0 + oo) * NI + i] = a;
  }
  __syncthreads();

  // ---- phase 3: PV. wave wid: i in [wid*64, wid*64+64), lane = 4 d's ----
  {
    const int d4 = lane;
    float4 av[OT];
#pragma unroll
    for (int oo = 0; oo < OT; ++oo) av[oo] = make_float4(0.f, 0.f, 0.f, 0.f);
    const float4* vb4 = (const float4*)(v + (size_t)b * NI * DIM);
#pragma unroll 2
    for (int ib = wid * 64; ib < wid * 64 + 64; ib += 4) {
      float sa[OT][4];
#pragma unroll
      for (int oo = 0; oo < OT; ++oo) f4arr(*(const float4*)&sc[oo][ib], sa[oo]);
#pragma unroll
      for (int j = 0; j < 4; ++j) {
        float4 vv = vb4[(size_t)(ib + j) * 64 + d4];
#pragma unroll
        for (int oo = 0; oo < OT; ++oo) {
          av[oo].x = fmaf(sa[oo][j], vv.x, av[oo].x);
          av[oo].y = fmaf(sa[oo][j], vv.y, av[oo].y);
          av[oo].z = fmaf(sa[oo][j], vv.z, av[oo].z);
          av[oo].w = fmaf(sa[oo][j], vv.w, av[oo].w);
        }
      }
    }
#pragma unroll
    for (int oo = 0; oo < OT; ++oo) *(float4*)&pvp[wid][oo][d4 * 4] = av[oo];
  }
  __syncthreads();
#pragma unroll
  for (int pp = 0; pp < 2; ++pp) {
    int flat = pp * 512 + t;
    int oo = flat >> 8, d = flat & 255;
    float sacc = 0.f;
#pragma unroll
    for (int w = 0; w < 8; ++w) sacc += pvp[w][oo][d];
    o0[oo][d] = sacc;
  }
  __syncthreads();

  // ---- phase 4: thread (oo = t>>8 in {0,1}, d): o's {oo, oo+2} share WfT col ----
  {
    const int oo = t >> 8;
    const int d  = t & 255;
    float f0 = 0.f, f1 = 0.f;
#pragma unroll 4
    for (int e4 = 0; e4 < 64; ++e4) {
      float oa[4], ob[4];
      f4arr(*(const float4*)&o0[oo][e4 * 4], oa);
      f4arr(*(const float4*)&o0[oo + 2][e4 * 4], ob);
#pragma unroll
      for (int c = 0; c < 4; ++c) {
        float wv = WfT[(size_t)(e4 * 4 + c) * DIM + d];
        f0 = fmaf(oa[c], wv, f0);
        f1 = fmaf(ob[c], wv, f1);
      }
    }
    float bfv = bf[d];
    f0 += bfv; f1 += bfv;
    f0 = (f0 >= 0.f) ? f0 : NEG_SLOPE * f0;
    f1 = (f1 >= 0.f) ? f1 : NEG_SLOPE * f1;
    out[(size_t)(bo0 + oo) * DIM + d]     = f0;
    out[(size_t)(bo0 + oo + 2) * DIM + d] = f1;
  }
}

// ---------------------------------------------------------------------------
extern "C" void kernel_launch(void* const* d_in, const int* in_sizes, int n_in,
                              void* d_out, int out_size, void* d_ws, size_t ws_size,
                              hipStream_t stream) {
  const float* q    = (const float*)d_in[0];
  const float* k    = (const float*)d_in[1];
  const float* v    = (const float*)d_in[2];
  const int*   mask = (const int*)d_in[3];
  const float* W1   = (const float*)d_in[4];
  const float* b1   = (const float*)d_in[5];
  const float* W2   = (const float*)d_in[6];
  const float* b2   = (const float*)d_in[7];
  const float* Wf   = (const float*)d_in[8];
  const float* bf   = (const float*)d_in[9];

  float* out      = (float*)d_out;                    // (16,64,256)
  float* attn_out = out + (size_t)BATCH * NO * DIM;   // (16,64,512)

  float* Eq  = (float*)d_ws;                          // 1024 x 256
  float* Ek4 = Eq + (size_t)BATCH * NO * DIM;         // 16 x 64 x 512 x 4
  float* WfT = Ek4 + (size_t)BATCH * DIM * NI;        // 256 x 256

  proj_kernel<<<592, 256, 0, stream>>>(q, k, W1, b1, Wf, Eq, Ek4, WfT);
  attn_kernel<<<(BATCH * NO) / OT, 512, 0, stream>>>(Eq, Ek4, v, mask, W2, b2,
                                                     WfT, bf, out, attn_out);
}

// Round 12
// 142.421 us; speedup vs baseline: 1.0225x; 1.0225x over previous
//
#include <hip/hip_runtime.h>
#include <math.h>

#define DIM 256
#define BATCH 16
#define NO 64
#define NI 512
#define NEG_SLOPE 0.01f
#define CSCALE 2.885390081777927f   // 2*log2(e): tanh(x) = 1 - 2/(exp2(CSCALE*x)+1)
#define OT 2                        // o's per attn thread

// ---------------------------------------------------------------------------
// Kernel 1 (blocks 0..575): GEMM  out[r,h] = sum_d A[r,d] * W1[h, coff+d]
//   rows 0..1023    -> Eq[bo][h]        = exp2(CSCALE*(acc + b1[h]))  (A = q)
//   rows 1024..9215 -> Ek4[b][h/4][i][4]= exp2(CSCALE*acc)            (A = k)
// exp factorization: e^{2(qp+kp+b1)} = Eq * Ek -> attn sigmoid = fma+rcp.
// 64x64 tile, K-chunk 64, 4x4 microtile. Blocks 576..591: Wf -> WfT.
// ---------------------------------------------------------------------------
__global__ __launch_bounds__(256, 4) void proj_kernel(
    const float* __restrict__ q, const float* __restrict__ k,
    const float* __restrict__ W1, const float* __restrict__ b1,
    const float* __restrict__ Wf,
    float* __restrict__ Eq, float* __restrict__ Ek4, float* __restrict__ WfT)
{
  __shared__ float smem[8704];   // 34 KB: At[64][68] + Wt[64][68]

  const int t  = threadIdx.x;
  const int bx = blockIdx.x;

  if (bx >= 576) {
    const int tt = bx - 576;
    const int tr = tt >> 2, tc = tt & 3;
#pragma unroll
    for (int p = 0; p < 4; ++p) {
      int idx = p * 256 + t;
      int row = idx >> 4, j = idx & 15;
      float4 vv = *(const float4*)(Wf + (size_t)(tr * 64 + row) * 256 + tc * 64 + j * 4);
      *(float4*)&smem[row * 68 + j * 4] = vv;
    }
    __syncthreads();
#pragma unroll
    for (int p = 0; p < 4; ++p) {
      int idx = p * 256 + t;
      int row = idx >> 4, j = idx & 15;
      float4 ov;
      ov.x = smem[(j * 4 + 0) * 68 + row];
      ov.y = smem[(j * 4 + 1) * 68 + row];
      ov.z = smem[(j * 4 + 2) * 68 + row];
      ov.w = smem[(j * 4 + 3) * 68 + row];
      *(float4*)(WfT + (size_t)(tc * 64 + row) * 256 + tr * 64 + j * 4) = ov;
    }
    return;
  }

  float* At = smem;            // At[dk][row], stride 68
  float* Wt = smem + 4352;     // Wt[dk][h],   stride 68

  const int tx = t & 15;
  const int ty = t >> 4;
  const int mt = bx >> 2;
  const int nt = bx & 3;
  const int r0 = mt * 64;
  const int h0 = nt * 64;
  const bool isq = (r0 < BATCH * NO);
  const float* src = isq ? (q + (size_t)r0 * DIM)
                         : (k + (size_t)(r0 - BATCH * NO) * DIM);
  const int coff = isq ? 0 : DIM;

  float acc[4][4] = {};

  for (int c0 = 0; c0 < DIM; c0 += 64) {
    __syncthreads();
#pragma unroll
    for (int p = 0; p < 4; ++p) {
      int idx = p * 256 + t;
      int row = idx >> 4, j = idx & 15;
      float4 av = *(const float4*)(src + (size_t)row * DIM + c0 + j * 4);
      At[(4 * j + 0) * 68 + row] = av.x;
      At[(4 * j + 1) * 68 + row] = av.y;
      At[(4 * j + 2) * 68 + row] = av.z;
      At[(4 * j + 3) * 68 + row] = av.w;
      float4 wv = *(const float4*)(W1 + (size_t)(h0 + row) * (2 * DIM) + coff + c0 + j * 4);
      Wt[(4 * j + 0) * 68 + row] = wv.x;
      Wt[(4 * j + 1) * 68 + row] = wv.y;
      Wt[(4 * j + 2) * 68 + row] = wv.z;
      Wt[(4 * j + 3) * 68 + row] = wv.w;
    }
    __syncthreads();
#pragma unroll
    for (int dk = 0; dk < 64; ++dk) {
      float4 a4 = *(const float4*)&At[dk * 68 + ty * 4];
      float4 w4 = *(const float4*)&Wt[dk * 68 + tx * 4];
      const float ar[4] = {a4.x, a4.y, a4.z, a4.w};
      const float wr[4] = {w4.x, w4.y, w4.z, w4.w};
#pragma unroll
      for (int rr = 0; rr < 4; ++rr)
#pragma unroll
        for (int cc = 0; cc < 4; ++cc)
          acc[rr][cc] = fmaf(ar[rr], wr[cc], acc[rr][cc]);
    }
  }

  if (isq) {
    float4 bv = *(const float4*)(b1 + h0 + tx * 4);
    const float br[4] = {bv.x, bv.y, bv.z, bv.w};
#pragma unroll
    for (int rr = 0; rr < 4; ++rr) {
      int r = r0 + ty * 4 + rr;
      float4 ov;
      ov.x = __builtin_amdgcn_exp2f((acc[rr][0] + br[0]) * CSCALE);
      ov.y = __builtin_amdgcn_exp2f((acc[rr][1] + br[1]) * CSCALE);
      ov.z = __builtin_amdgcn_exp2f((acc[rr][2] + br[2]) * CSCALE);
      ov.w = __builtin_amdgcn_exp2f((acc[rr][3] + br[3]) * CSCALE);
      *(float4*)(Eq + (size_t)r * DIM + h0 + tx * 4) = ov;
    }
  } else {
    // Ek4 layout: Ek4[((b*64 + h/4)*NI + i)*4 + (h&3)]
    int ig0 = r0 - BATCH * NO;
    int b   = ig0 >> 9;
    int i0  = (ig0 & 511) + ty * 4;
    int hq0 = (h0 >> 2) + tx;          // this thread's h-quad
#pragma unroll
    for (int rr = 0; rr < 4; ++rr) {
      float4 ov;
      ov.x = __builtin_amdgcn_exp2f(acc[rr][0] * CSCALE);
      ov.y = __builtin_amdgcn_exp2f(acc[rr][1] * CSCALE);
      ov.z = __builtin_amdgcn_exp2f(acc[rr][2] * CSCALE);
      ov.w = __builtin_amdgcn_exp2f(acc[rr][3] * CSCALE);
      *(float4*)(Ek4 + ((size_t)(b * 64 + hq0) * NI + i0 + rr) * 4) = ov;
    }
  }
}

__device__ __forceinline__ void f4arr(float4 v, float* a) {
  a[0] = v.x; a[1] = v.y; a[2] = v.z; a[3] = v.w;
}

// ---------------------------------------------------------------------------
// Kernel 2: one block (512 threads) per (b, o-pair). Grid 512 (2 blocks/CU,
// 16 waves/CU). XCD-swizzled (2 b's per XCD -> Ek+v hot set < 4 MB L2).
// phase 1: paired-rcp sigmoid: w_a/A + w_b/B = (w_a*B + w_b*A)*rcp(A*B)
//          -> 1 transcendental per 2 sigmoids. One Ek4 float4 load per 4 h.
// phase 2: 2 softmaxes, no max-subtraction (|s| <= sum|W2|+|b2| ~ 13).
// phase 3: PV. phase 4: both o's per thread, shared WfT column.
// ---------------------------------------------------------------------------
__global__ __launch_bounds__(512, 4) void attn_kernel(
    const float* __restrict__ Eq, const float* __restrict__ Ek4,
    const float* __restrict__ v, const int* __restrict__ mask,
    const float* __restrict__ W2, const float* __restrict__ b2,
    const float* __restrict__ WfT, const float* __restrict__ bf,
    float* __restrict__ out, float* __restrict__ attn_out)
{
  __shared__ float sc[OT][NI];        // 4 KB
  __shared__ float pvp[8][OT][DIM];   // 16 KB
  __shared__ float o0[OT][DIM];       // 2 KB
  __shared__ float red4[8][OT];
  __shared__ float redw[8];

  const int t    = threadIdx.x;
  const int lane = t & 63;
  const int wid  = t >> 6;

  const int blk  = blockIdx.x;
  const int tile = (blk & 7) * 64 + (blk >> 3);   // XCD swizzle
  const int b    = tile >> 5;
  const int bo0  = b * 64 + (tile & 31) * OT;

  // ---- sumW2 ----
  float partial = (t < DIM) ? W2[t] : 0.f;
#pragma unroll
  for (int off = 32; off >= 1; off >>= 1) partial += __shfl_xor(partial, off, 64);
  if (lane == 0) redw[wid] = partial;
  __syncthreads();
  float sumw2 = 0.f;
#pragma unroll
  for (int w = 0; w < 8; ++w) sumw2 += redw[w];
  const float base = sumw2 + b2[0];

  // ---- phase 1: scores s0,s1 for i = t (paired-rcp) ----
  const int i = t;
  const float4* kb4 = (const float4*)Ek4 + (size_t)b * 64 * NI;  // [hq*NI + i]
  const float* qrow0 = Eq + (size_t)(bo0 + 0) * DIM;
  const float* qrow1 = Eq + (size_t)(bo0 + 1) * DIM;

  float acc0 = 0.f, acc1 = 0.f;
#pragma unroll 8
  for (int hq = 0; hq < 64; ++hq) {
    float4 kq = kb4[(size_t)hq * NI + i];
    float wr[4], q0r[4], q1r[4], kv[4];
    f4arr(*(const float4*)(W2 + hq * 4), wr);        // wave-uniform -> s_load
    f4arr(*(const float4*)(qrow0 + hq * 4), q0r);
    f4arr(*(const float4*)(qrow1 + hq * 4), q1r);
    f4arr(kq, kv);
#pragma unroll
    for (int pr = 0; pr < 2; ++pr) {                 // pairs (0,1) and (2,3)
      const int ea = pr * 2, eb = pr * 2 + 1;
      // o0: wa/A + wb/B = (wa*B + wb*A) * rcp(A*B)
      float A0 = fmaf(q0r[ea], kv[ea], 1.f);
      float B0 = fmaf(q0r[eb], kv[eb], 1.f);
      float N0 = fmaf(wr[eb], A0, wr[ea] * B0);
      acc0 = fmaf(N0, __builtin_amdgcn_rcpf(A0 * B0), acc0);
      // o1
      float A1 = fmaf(q1r[ea], kv[ea], 1.f);
      float B1 = fmaf(q1r[eb], kv[eb], 1.f);
      float N1 = fmaf(wr[eb], A1, wr[ea] * B1);
      acc1 = fmaf(N1, __builtin_amdgcn_rcpf(A1 * B1), acc1);
    }
  }

  const int mv = mask[(size_t)b * NI + i];
  float s0 = base - 2.f * acc0;
  float s1 = base - 2.f * acc1;
  if (mv) { s0 = -INFINITY; s1 = -INFINITY; }

  // ---- phase 2: 2 softmaxes over 512 lanes, no max-subtraction ----
  // |s| <= sum|W2| + |b2| ~ 13 -> exp2 safe; exp2(-inf) = 0 for masked.
  float p0 = __builtin_amdgcn_exp2f(s0 * 1.4426950408889634f);
  float p1 = __builtin_amdgcn_exp2f(s1 * 1.4426950408889634f);
  float ps0 = p0, ps1 = p1;
#pragma unroll
  for (int off = 32; off >= 1; off >>= 1) {
    ps0 += __shfl_xor(ps0, off, 64);
    ps1 += __shfl_xor(ps1, off, 64);
  }
  __syncthreads();               // redw reads done; red4 safe
  if (lane == 0) { red4[wid][0] = ps0; red4[wid][1] = ps1; }
  __syncthreads();
  float ss0 = 0.f, ss1 = 0.f;
#pragma unroll
  for (int w = 0; w < 8; ++w) { ss0 += red4[w][0]; ss1 += red4[w][1]; }
  const float a0 = p0 * __builtin_amdgcn_rcpf(ss0);
  const float a1 = p1 * __builtin_amdgcn_rcpf(ss1);
  sc[0][i] = a0;
  sc[1][i] = a1;
  attn_out[(size_t)(bo0 + 0) * NI + i] = a0;
  attn_out[(size_t)(bo0 + 1) * NI + i] = a1;
  __syncthreads();

  // ---- phase 3: PV. wave wid: i in [wid*64, wid*64+64), lane = 4 d's ----
  {
    const int d4 = lane;
    float4 av0 = {0.f, 0.f, 0.f, 0.f};
    float4 av1 = {0.f, 0.f, 0.f, 0.f};
    const float4* vb4 = (const float4*)(v + (size_t)b * NI * DIM);
#pragma unroll 2
    for (int ib = wid * 64; ib < wid * 64 + 64; ib += 4) {
      float sa0[4], sa1[4];
      f4arr(*(const float4*)&sc[0][ib], sa0);
      f4arr(*(const float4*)&sc[1][ib], sa1);
#pragma unroll
      for (int j = 0; j < 4; ++j) {
        float4 vv = vb4[(size_t)(ib + j) * 64 + d4];
        av0.x = fmaf(sa0[j], vv.x, av0.x);
        av0.y = fmaf(sa0[j], vv.y, av0.y);
        av0.z = fmaf(sa0[j], vv.z, av0.z);
        av0.w = fmaf(sa0[j], vv.w, av0.w);
        av1.x = fmaf(sa1[j], vv.x, av1.x);
        av1.y = fmaf(sa1[j], vv.y, av1.y);
        av1.z = fmaf(sa1[j], vv.z, av1.z);
        av1.w = fmaf(sa1[j], vv.w, av1.w);
      }
    }
    *(float4*)&pvp[wid][0][d4 * 4] = av0;
    *(float4*)&pvp[wid][1][d4 * 4] = av1;
  }
  __syncthreads();
  {
    int oo = t >> 8, d = t & 255;
    float sacc = 0.f;
#pragma unroll
    for (int w = 0; w < 8; ++w) sacc += pvp[w][oo][d];
    o0[oo][d] = sacc;
  }
  __syncthreads();

  // ---- phase 4: threads t<256 compute BOTH o's, one WfT column load ----
  if (t < DIM) {
    const int d = t;
    float f0 = 0.f, f1 = 0.f;
#pragma unroll 8
    for (int e4 = 0; e4 < 64; ++e4) {
      float oa[4], ob[4];
      f4arr(*(const float4*)&o0[0][e4 * 4], oa);
      f4arr(*(const float4*)&o0[1][e4 * 4], ob);
#pragma unroll
      for (int c = 0; c < 4; ++c) {
        float wv = WfT[(size_t)(e4 * 4 + c) * DIM + d];
        f0 = fmaf(oa[c], wv, f0);
        f1 = fmaf(ob[c], wv, f1);
      }
    }
    float bfv = bf[d];
    f0 += bfv; f1 += bfv;
    f0 = (f0 >= 0.f) ? f0 : NEG_SLOPE * f0;
    f1 = (f1 >= 0.f) ? f1 : NEG_SLOPE * f1;
    out[(size_t)(bo0 + 0) * DIM + d] = f0;
    out[(size_t)(bo0 + 1) * DIM + d] = f1;
  }
}

// ---------------------------------------------------------------------------
extern "C" void kernel_launch(void* const* d_in, const int* in_sizes, int n_in,
                              void* d_out, int out_size, void* d_ws, size_t ws_size,
                              hipStream_t stream) {
  const float* q    = (const float*)d_in[0];
  const float* k    = (const float*)d_in[1];
  const float* v    = (const float*)d_in[2];
  const int*   mask = (const int*)d_in[3];
  const float* W1   = (const float*)d_in[4];
  const float* b1   = (const float*)d_in[5];
  const float* W2   = (const float*)d_in[6];
  const float* b2   = (const float*)d_in[7];
  const float* Wf   = (const float*)d_in[8];
  const float* bf   = (const float*)d_in[9];

  float* out      = (float*)d_out;                    // (16,64,256)
  float* attn_out = out + (size_t)BATCH * NO * DIM;   // (16,64,512)

  float* Eq  = (float*)d_ws;                          // 1024 x 256
  float* Ek4 = Eq + (size_t)BATCH * NO * DIM;         // 16 x 64 x 512 x 4
  float* WfT = Ek4 + (size_t)BATCH * DIM * NI;        // 256 x 256

  proj_kernel<<<592, 256, 0, stream>>>(q, k, W1, b1, Wf, Eq, Ek4, WfT);
  attn_kernel<<<(BATCH * NO) / OT, 512, 0, stream>>>(Eq, Ek4, v, mask, W2, b2,
                                                     WfT, bf, out, attn_out);
}